// Round 3
// baseline (875.756 us; speedup 1.0000x reference)
//
#include <hip/hip_runtime.h>
#include <hip/hip_bf16.h>

// DynamicMoE (expert-choice) MI355X. B=4,S=2048,H=1024,F=4096,E=8 -> N=8192,k=1280.
// R3: histogram top-k (replaces 8-block bitonic), gemm2 split-K=2, gate+cvt fused.

#define H_DIM 1024
#define F_DIM 4096
#define E_NUM 8
#define N_TOK 8192
#define K_CAP 1280

typedef __bf16 bf16x8 __attribute__((ext_vector_type(8)));
typedef float f32x4 __attribute__((ext_vector_type(4)));
typedef unsigned short us4 __attribute__((ext_vector_type(4)));
typedef unsigned long long u64;

__device__ __forceinline__ unsigned short f2bf(float f) {
  unsigned u = __float_as_uint(f);
  unsigned r = u + 0x7FFFu + ((u >> 16) & 1u);   // RNE
  return (unsigned short)(r >> 16);
}

__device__ __forceinline__ unsigned sortable(float f) {
  unsigned u = __float_as_uint(f);
  return (u & 0x80000000u) ? ~u : (u | 0x80000000u);
}

__device__ __forceinline__ void async_copy16(void* lds, const void* g) {
  __builtin_amdgcn_global_load_lds(
      (const __attribute__((address_space(1))) unsigned int*)g,
      (__attribute__((address_space(3))) unsigned int*)lds, 16, 0, 0);
}

// ------------- transpose+convert: src[e][R][C] f32 -> dst[e][C][R] bf16 -----
__global__ __launch_bounds__(256) void k_transpose(const float* __restrict__ src,
                                                   unsigned short* __restrict__ dst,
                                                   int R, int C) {
  const int e = blockIdx.z;
  src += (size_t)e * R * C;
  dst += (size_t)e * R * C;
  const int c0 = blockIdx.x * 64;
  const int r0 = blockIdx.y * 64;
  __shared__ unsigned short Ls[64][72];
  const int t = threadIdx.x;
  const int mr = (t >> 4) << 2;
  const int mc = (t & 15) << 2;
  union { float4 q; float f[4]; } v[4];
#pragma unroll
  for (int rr = 0; rr < 4; ++rr)
    v[rr].q = *(const float4*)(src + (size_t)(r0 + mr + rr) * C + c0 + mc);
#pragma unroll
  for (int cc = 0; cc < 4; ++cc) {
    us4 u;
    u.x = f2bf(v[0].f[cc]); u.y = f2bf(v[1].f[cc]);
    u.z = f2bf(v[2].f[cc]); u.w = f2bf(v[3].f[cc]);
    *(us4*)&Ls[mc + cc][mr] = u;
  }
  __syncthreads();
  const int oc = t >> 2;
  const int or_ = (t & 3) * 16;
  uint4 w0 = *(const uint4*)&Ls[oc][or_];
  uint4 w1 = *(const uint4*)&Ls[oc][or_ + 8];
  unsigned short* dp = dst + (size_t)(c0 + oc) * R + r0 + or_;
  *(uint4*)dp = w0;
  *(uint4*)(dp + 8) = w1;
}

// -------- gate: logits[N,E] fp64 acc + fused x->bf16 cast --------
__global__ __launch_bounds__(256) void k_gate(const float* __restrict__ x,
                                              const float* __restrict__ gw,
                                              float* __restrict__ logits,
                                              unsigned short* __restrict__ xb) {
  int lane = threadIdx.x & 63;
  int wave = threadIdx.x >> 6;
  int token = blockIdx.x * 4 + wave;
  const float* xr = x + (size_t)token * H_DIM;
  unsigned short* xbr = xb + (size_t)token * H_DIM;
  double acc[E_NUM];
#pragma unroll
  for (int e = 0; e < E_NUM; ++e) acc[e] = 0.0;
  for (int i = lane; i < H_DIM; i += 64) {
    float xf = xr[i];
    xbr[i] = f2bf(xf);
    double xv = (double)xf;
    const float* g = gw + (size_t)i * E_NUM;
#pragma unroll
    for (int e = 0; e < E_NUM; ++e) acc[e] += xv * (double)g[e];
  }
#pragma unroll
  for (int off = 32; off > 0; off >>= 1) {
#pragma unroll
    for (int e = 0; e < E_NUM; ++e) acc[e] += __shfl_down(acc[e], off, 64);
  }
  if (lane == 0) {
#pragma unroll
    for (int e = 0; e < E_NUM; ++e)
      logits[(size_t)token * E_NUM + e] = (float)acc[e];
  }
}

// -------- top-k via 16-bit histogram selection --------
// hist[e][65536] built from top-16 bits of sortable key.
__global__ __launch_bounds__(256) void k_hist(const float* __restrict__ logits,
                                              unsigned* __restrict__ hist) {
  const int e = blockIdx.x >> 3;
  const int c0 = (blockIdx.x & 7) * 1024;
  unsigned* h = hist + (size_t)e * 65536;
#pragma unroll
  for (int r = 0; r < 4; ++r) {
    int t = c0 + threadIdx.x + r * 256;
    unsigned key = sortable(logits[(size_t)t * E_NUM + e]);
    atomicAdd(&h[key >> 16], 1u);
  }
}

__global__ __launch_bounds__(256) void k_thresh(const unsigned* __restrict__ hist,
                                                int* __restrict__ meta) {
  const int e = blockIdx.x;
  const int t = threadIdx.x;
  __shared__ unsigned gsum[256];
  const unsigned* h = hist + (size_t)e * 65536;
  unsigned s = 0;
  const unsigned* hp = h + t * 256;
  for (int i = 0; i < 256; ++i) s += hp[i];
  gsum[t] = s;
  __syncthreads();
  if (t == 0) {
    unsigned acc = 0;
    int g = 255;
    while (acc + gsum[g] < K_CAP) { acc += gsum[g]; --g; }
    const unsigned* hh = h + g * 256;
    int b = 255;
    while (acc + hh[b] < K_CAP) { acc += hh[b]; --b; }
    meta[16 + e] = g * 256 + b;        // thr16
    meta[24 + e] = (int)acc;           // n_gt
    meta[32 + e] = K_CAP - (int)acc;   // need
  }
}

__global__ __launch_bounds__(256) void k_emit(const float* __restrict__ logits,
                                              int* __restrict__ meta,
                                              u64* __restrict__ side,
                                              int* __restrict__ idx_out) {
  const int e = blockIdx.x >> 3;
  const int c0 = (blockIdx.x & 7) * 1024;
  const unsigned T = (unsigned)meta[16 + e];
  int* pos = meta;          // [0..7] zeroed
  int* scnt = meta + 8;     // [8..15] zeroed
#pragma unroll
  for (int r = 0; r < 4; ++r) {
    int t = c0 + threadIdx.x + r * 256;
    unsigned key = sortable(logits[(size_t)t * E_NUM + e]);
    unsigned k16 = key >> 16;
    if (k16 > T) {
      int p = atomicAdd(&pos[e], 1);
      idx_out[e * K_CAP + p] = t;
    } else if (k16 == T) {
      int q = atomicAdd(&scnt[e], 1);
      if (q < 4096) side[(size_t)e * 4096 + q] = ((u64)key << 32) | (unsigned)(~t);
    }
  }
}

__global__ __launch_bounds__(256) void k_bound(const int* __restrict__ meta,
                                               const u64* __restrict__ side,
                                               int* __restrict__ idx_out) {
  const int e = blockIdx.x;
  const int tid = threadIdx.x;
  int n = meta[8 + e]; if (n > 4096) n = 4096;
  const int ng = meta[24 + e];
  const int nd = meta[32 + e];
  __shared__ u64 S[4096];
  for (int i = tid; i < 4096; i += 256)
    S[i] = (i < n) ? side[(size_t)e * 4096 + i] : 0ull;
  for (unsigned size = 2; size <= 4096; size <<= 1) {
    for (unsigned stride = size >> 1; stride > 0; stride >>= 1) {
      __syncthreads();
      for (unsigned i = tid; i < 4096; i += 256) {
        unsigned j = i ^ stride;
        if (j > i) {
          u64 a = S[i], b = S[j];
          bool desc = ((i & size) == 0);
          if (desc ? (a < b) : (a > b)) { S[i] = b; S[j] = a; }
        }
      }
    }
  }
  __syncthreads();
  for (int q = tid; q < nd; q += 256)
    idx_out[e * K_CAP + ng + q] = (int)(~(unsigned)(S[q] & 0xFFFFFFFFull));
}

// ---- GEMM1: h = silu(gather(xb) @ w1t^T), 128x128xBK32, global_load_lds ----
__global__ __launch_bounds__(256) void k_gemm1(const unsigned short* __restrict__ xb,
                                               const int* __restrict__ idx,
                                               const unsigned short* __restrict__ w1t,
                                               unsigned short* __restrict__ hbuf) {
  const int m0 = blockIdx.x * 128;
  const int n0 = blockIdx.y * 128;
  const int e  = blockIdx.z;
  const int tid = threadIdx.x;
  const int wave = tid >> 6;
  const int lane = tid & 63;

  __shared__ __align__(16) unsigned short As[128 * 32];
  __shared__ __align__(16) unsigned short Bs[128 * 32];

  const int srow = wave * 32 + (lane >> 2);
  const int kcol = (lane & 3) * 8;
  const int tok0 = idx[e * K_CAP + m0 + srow];
  const int tok1 = idx[e * K_CAP + m0 + srow + 16];
  const unsigned short* ag0 = xb + (size_t)tok0 * H_DIM + kcol;
  const unsigned short* ag1 = xb + (size_t)tok1 * H_DIM + kcol;
  const unsigned short* wbase = w1t + (size_t)e * F_DIM * H_DIM;
  const unsigned short* bg0 = wbase + (size_t)(n0 + srow) * H_DIM + kcol;
  const unsigned short* bg1 = wbase + (size_t)(n0 + srow + 16) * H_DIM + kcol;
  unsigned short* la0 = As + (wave * 32) * 32;
  unsigned short* la1 = As + (wave * 32 + 16) * 32;
  unsigned short* lb0 = Bs + (wave * 32) * 32;
  unsigned short* lb1 = Bs + (wave * 32 + 16) * 32;

  const int wm = (wave & 1) * 64;
  const int wn = (wave >> 1) * 64;
  const int lrow = lane & 15;
  const int quad = lane >> 4;

  f32x4 acc[4][4];
#pragma unroll
  for (int i = 0; i < 4; ++i)
#pragma unroll
    for (int j = 0; j < 4; ++j) acc[i][j] = (f32x4){0.f, 0.f, 0.f, 0.f};

  for (int k0 = 0; k0 < H_DIM; k0 += 32) {
    __syncthreads();
    async_copy16(la0, ag0 + k0);
    async_copy16(la1, ag1 + k0);
    async_copy16(lb0, bg0 + k0);
    async_copy16(lb1, bg1 + k0);
    __syncthreads();

    bf16x8 af[4], bfr[4];
#pragma unroll
    for (int i = 0; i < 4; ++i)
      af[i] = *(const bf16x8*)&As[(wm + i * 16 + lrow) * 32 + quad * 8];
#pragma unroll
    for (int j = 0; j < 4; ++j)
      bfr[j] = *(const bf16x8*)&Bs[(wn + j * 16 + lrow) * 32 + quad * 8];
#pragma unroll
    for (int i = 0; i < 4; ++i)
#pragma unroll
      for (int j = 0; j < 4; ++j)
        acc[i][j] = __builtin_amdgcn_mfma_f32_16x16x32_bf16(af[i], bfr[j], acc[i][j], 0, 0, 0);
  }

  unsigned short* hrow = hbuf + (size_t)e * K_CAP * F_DIM;
#pragma unroll
  for (int i = 0; i < 4; ++i) {
#pragma unroll
    for (int j = 0; j < 4; ++j) {
#pragma unroll
      for (int r = 0; r < 4; ++r) {
        int gm = m0 + wm + i * 16 + quad * 4 + r;
        int gn = n0 + wn + j * 16 + lrow;
        float v = acc[i][j][r];
        float s = v / (1.f + __expf(-v));
        hrow[(size_t)gm * F_DIM + gn] = f2bf(s);
      }
    }
  }
}

// ---- GEMM2: out[tok] += h @ w2t^T, split-K=2, scatter atomics ----
__global__ __launch_bounds__(256) void k_gemm2(const unsigned short* __restrict__ hbuf,
                                               const int* __restrict__ idx,
                                               const unsigned short* __restrict__ w2t,
                                               float* __restrict__ out) {
  const int m0 = blockIdx.x * 128;
  const int n0 = blockIdx.y * 128;
  const int e  = blockIdx.z >> 1;
  const int koff = (blockIdx.z & 1) * (F_DIM / 2);
  const int tid = threadIdx.x;
  const int wave = tid >> 6;
  const int lane = tid & 63;

  __shared__ __align__(16) unsigned short As[128 * 32];
  __shared__ __align__(16) unsigned short Bs[128 * 32];
  __shared__ int toks[128];
  if (tid < 128) toks[tid] = idx[e * K_CAP + m0 + tid];

  const int srow = wave * 32 + (lane >> 2);
  const int kcol = (lane & 3) * 8;
  const unsigned short* ag0 = hbuf + ((size_t)e * K_CAP + m0 + srow) * F_DIM + kcol;
  const unsigned short* ag1 = ag0 + (size_t)16 * F_DIM;
  const unsigned short* wbase = w2t + (size_t)e * H_DIM * F_DIM;
  const unsigned short* bg0 = wbase + (size_t)(n0 + srow) * F_DIM + kcol;
  const unsigned short* bg1 = bg0 + (size_t)16 * F_DIM;
  unsigned short* la0 = As + (wave * 32) * 32;
  unsigned short* la1 = As + (wave * 32 + 16) * 32;
  unsigned short* lb0 = Bs + (wave * 32) * 32;
  unsigned short* lb1 = Bs + (wave * 32 + 16) * 32;

  const int wm = (wave & 1) * 64;
  const int wn = (wave >> 1) * 64;
  const int lrow = lane & 15;
  const int quad = lane >> 4;

  f32x4 acc[4][4];
#pragma unroll
  for (int i = 0; i < 4; ++i)
#pragma unroll
    for (int j = 0; j < 4; ++j) acc[i][j] = (f32x4){0.f, 0.f, 0.f, 0.f};

  for (int k0 = koff; k0 < koff + F_DIM / 2; k0 += 32) {
    __syncthreads();
    async_copy16(la0, ag0 + k0);
    async_copy16(la1, ag1 + k0);
    async_copy16(lb0, bg0 + k0);
    async_copy16(lb1, bg1 + k0);
    __syncthreads();

    bf16x8 af[4], bfr[4];
#pragma unroll
    for (int i = 0; i < 4; ++i)
      af[i] = *(const bf16x8*)&As[(wm + i * 16 + lrow) * 32 + quad * 8];
#pragma unroll
    for (int j = 0; j < 4; ++j)
      bfr[j] = *(const bf16x8*)&Bs[(wn + j * 16 + lrow) * 32 + quad * 8];
#pragma unroll
    for (int i = 0; i < 4; ++i)
#pragma unroll
      for (int j = 0; j < 4; ++j)
        acc[i][j] = __builtin_amdgcn_mfma_f32_16x16x32_bf16(af[i], bfr[j], acc[i][j], 0, 0, 0);
  }

#pragma unroll
  for (int i = 0; i < 4; ++i) {
#pragma unroll
    for (int r = 0; r < 4; ++r) {
      int lm = wm + i * 16 + quad * 4 + r;
      int token = toks[lm];
      float* orow = out + (size_t)token * H_DIM;
#pragma unroll
      for (int j = 0; j < 4; ++j) {
        int gn = n0 + wn + j * 16 + lrow;
        atomicAdd(&orow[gn], acc[i][j][r]);
      }
    }
  }
}

extern "C" void kernel_launch(void* const* d_in, const int* in_sizes, int n_in,
                              void* d_out, int out_size, void* d_ws, size_t ws_size,
                              hipStream_t stream) {
  const float* x  = (const float*)d_in[0];
  const float* gw = (const float*)d_in[1];
  const float* w1 = (const float*)d_in[2];
  const float* w2 = (const float*)d_in[3];
  float* out = (float*)d_out;

  char* ws = (char*)d_ws;
  float* logits = (float*)(ws + 0x0);              // 256 KB
  int* idx      = (int*)(ws + 0x40000);            // 40 KB
  int* meta     = (int*)(ws + 0x50000);            // 4 KB (pos[8],scnt[8],thr[8],ngt[8],need[8])
  unsigned* hist = (unsigned*)(ws + 0x51000);      // 2 MB
  u64* side     = (u64*)(ws + 0x251000);           // 256 KB
  unsigned short* xb   = (unsigned short*)(ws + 0x2A0000);   // 16 MB
  unsigned short* w1t  = (unsigned short*)(ws + 0x12A0000);  // 64 MB
  unsigned short* w2t  = (unsigned short*)(ws + 0x52A0000);  // 64 MB
  unsigned short* hbuf = (unsigned short*)(ws + 0x92A0000);  // 80 MB

  hipMemsetAsync(d_out, 0, (size_t)out_size * sizeof(float), stream);
  hipMemsetAsync(ws + 0x50000, 0, 0x201000, stream);  // meta + hist

  k_gate<<<dim3(N_TOK / 4), 256, 0, stream>>>(x, gw, logits, xb);
  k_transpose<<<dim3(F_DIM / 64, H_DIM / 64, E_NUM), 256, 0, stream>>>(w1, w1t, H_DIM, F_DIM);
  k_transpose<<<dim3(H_DIM / 64, F_DIM / 64, E_NUM), 256, 0, stream>>>(w2, w2t, F_DIM, H_DIM);
  k_hist<<<dim3(64), 256, 0, stream>>>(logits, hist);
  k_thresh<<<dim3(E_NUM), 256, 0, stream>>>(hist, meta);
  k_emit<<<dim3(64), 256, 0, stream>>>(logits, meta, side, idx);
  k_bound<<<dim3(E_NUM), 256, 0, stream>>>(meta, side, idx);
  k_gemm1<<<dim3(K_CAP / 128, F_DIM / 128, E_NUM), 256, 0, stream>>>(xb, idx, w1t, hbuf);
  k_gemm2<<<dim3(K_CAP / 128, H_DIM / 128, E_NUM * 2), 256, 0, stream>>>(hbuf, idx, w2t, out);
}